// Round 1
// baseline (303.515 us; speedup 1.0000x reference)
//
#include <hip/hip_runtime.h>
#include <hip/hip_bf16.h>
#include <math.h>

// Problem dims (hardcoded to reference setup)
// x: [4,128,256,256] f32; conv_w: [4,128,128]; conv_g/b: [4,128]
// final_w: [128,640]; final_g/b: [128]; out: [4,128,256,256] f32
#define B_ 4
#define C_ 128
#define P_ 65536
#define NCH 512  // B_*C_

// ---- workspace float offsets ----
// M levels (block maxima), level d has NCH*4^d floats. Order: M3,M2,M1,M0
// rel(d) = 43520 - 512*((4^(d+1)-1)/3):  d3->0, d2->32768, d1->40960, d0->43008
#define YBASE_      43520   // y levels, same internal layout as M
#define SCALED_OFF  87040   // [4][128] per-branch BN scale
#define SHIFTD_OFF  87552   // [4][128] per-branch BN shift
#define CONTRIB_OFF 88064   // [B][C][64]
#define W0T_OFF     120832  // [128 c][128 o] transposed first block of final_w
#define PSUM_OFF    137216  // [128 o][4096 wg]
#define PSS_OFF     661504  // [128 o][4096 wg]
#define SCALEF_OFF  1185792 // [128]
#define SHIFTF_OFF  1185920 // [128]
// total floats: 1186048  (~4.53 MB)

__device__ __forceinline__ int level_rel(int d) {
    return YBASE_ - 512 * (((1 << (2 * (d + 1))) - 1) / 3);
}

// K0: transpose first 128 columns of final_w -> W0t[c][o]
__global__ __launch_bounds__(256) void k_w0t(const float* __restrict__ final_w,
                                             float* __restrict__ ws) {
    int idx = blockIdx.x * 256 + threadIdx.x;  // 16384
    if (idx >= 16384) return;
    int c = idx >> 7, o = idx & 127;
    ws[W0T_OFF + idx] = final_w[(size_t)o * 640 + c];
}

// K1: 32x32 block maxima M3[b][c][64]. grid = B*C*8 (one 32-row stripe each)
__global__ __launch_bounds__(256) void k_blockmax(const float* __restrict__ x,
                                                  float* __restrict__ ws) {
    int bid = blockIdx.x;
    int i3 = bid & 7;
    int bc = bid >> 3;
    const float* xp = x + (size_t)bc * P_ + (size_t)i3 * 32 * 256;
    int t = threadIdx.x;
    int r = t >> 3, q = t & 7;
    int lane = t & 63, wv = t >> 6;
    __shared__ float wred[4];
    for (int j3 = 0; j3 < 8; ++j3) {
        float4 v = *(const float4*)(xp + r * 256 + j3 * 32 + q * 4);
        float m = fmaxf(fmaxf(v.x, v.y), fmaxf(v.z, v.w));
#pragma unroll
        for (int s = 1; s < 64; s <<= 1) m = fmaxf(m, __shfl_xor(m, s));
        if (lane == 0) wred[wv] = m;
        __syncthreads();
        if (t == 0) {
            float mm = fmaxf(fmaxf(wred[0], wred[1]), fmaxf(wred[2], wred[3]));
            ws[(size_t)bc * 64 + i3 * 8 + j3] = mm;  // M3 at rel 0
        }
        __syncthreads();
    }
}

// K2: build M2/M1/M0 from M3. one thread per (b,c)
__global__ __launch_bounds__(256) void k_levels(float* __restrict__ ws) {
    int bc = blockIdx.x * 256 + threadIdx.x;
    if (bc >= NCH) return;
    const float* M3 = ws + (size_t)bc * 64;
    float* M2 = ws + 32768 + (size_t)bc * 16;
    float* M1 = ws + 40960 + (size_t)bc * 4;
    float* M0 = ws + 43008 + bc;
    float m2[16];
#pragma unroll
    for (int i2 = 0; i2 < 4; ++i2)
#pragma unroll
        for (int j2 = 0; j2 < 4; ++j2) {
            float m = -3.402823466e38f;
            for (int a = 0; a < 2; ++a)
                for (int b2 = 0; b2 < 2; ++b2)
                    m = fmaxf(m, M3[(2 * i2 + a) * 8 + (2 * j2 + b2)]);
            m2[i2 * 4 + j2] = m;
            M2[i2 * 4 + j2] = m;
        }
    float m1[4];
#pragma unroll
    for (int i1 = 0; i1 < 2; ++i1)
#pragma unroll
        for (int j1 = 0; j1 < 2; ++j1) {
            float m = -3.402823466e38f;
            for (int a = 0; a < 2; ++a)
                for (int b2 = 0; b2 < 2; ++b2)
                    m = fmaxf(m, m2[(2 * i1 + a) * 4 + (2 * j1 + b2)]);
            m1[i1 * 2 + j1] = m;
            M1[i1 * 2 + j1] = m;
        }
    M0[0] = fmaxf(fmaxf(m1[0], m1[1]), fmaxf(m1[2], m1[3]));
}

// K3a: y_d[b,co,blk] = sum_ci M_d[b,ci,blk] * conv_w[d][co][ci]
// grid = 4(d) * 4(b) * 4(co-chunk of 32), block 256
__global__ __launch_bounds__(256) void k_conv_pool(const float* __restrict__ conv_w,
                                                   float* __restrict__ ws) {
    int bid = blockIdx.x;
    int d = bid >> 4, b = (bid >> 2) & 3, cchunk = bid & 3;
    int NB = 1 << (2 * d);
    int rel = level_rel(d);
    const float* Mb = ws + rel + (size_t)b * 128 * NB;
    float* Yb = ws + YBASE_ + rel + (size_t)b * 128 * NB;
    __shared__ float mlds[8192];
    int t = threadIdx.x;
    int tot = 128 * NB;
    for (int i = t; i < tot; i += 256) mlds[i] = Mb[i];
    __syncthreads();
    if (NB >= 4) {
        int nbq = NB >> 2;                 // quads per co
        int nq = 32 * nbq;                 // outputs quads this chunk
        for (int qi = t; qi < nq; qi += 256) {
            int co = cchunk * 32 + (qi >> (2 * d - 2));
            int bq = qi & (nbq - 1);
            const float* wrow = conv_w + ((size_t)d * 128 + co) * 128;
            float a0 = 0.f, a1 = 0.f, a2 = 0.f, a3 = 0.f;
            for (int ci = 0; ci < 128; ++ci) {
                float4 mv = *(const float4*)(&mlds[ci * NB + bq * 4]);
                float wvv = wrow[ci];
                a0 = fmaf(wvv, mv.x, a0);
                a1 = fmaf(wvv, mv.y, a1);
                a2 = fmaf(wvv, mv.z, a2);
                a3 = fmaf(wvv, mv.w, a3);
            }
            float4 r;
            r.x = a0; r.y = a1; r.z = a2; r.w = a3;
            *(float4*)(&Yb[co * NB + bq * 4]) = r;
        }
    } else {  // d == 0, NB == 1
        for (int oi = t; oi < 32; oi += 256) {
            int co = cchunk * 32 + oi;
            const float* wrow = conv_w + (size_t)co * 128;  // d==0
            float acc = 0.f;
            for (int ci = 0; ci < 128; ++ci) acc = fmaf(mlds[ci], wrow[ci], acc);
            Yb[co] = acc;
        }
    }
}

// K3b: per-(d,c) BN stats over (b,blk) -> scale/shift
__global__ __launch_bounds__(256) void k_bnstats_d(const float* __restrict__ conv_g,
                                                   const float* __restrict__ conv_b,
                                                   float* __restrict__ ws) {
    int tid = blockIdx.x * 256 + threadIdx.x;
    if (tid >= 512) return;
    int d = tid >> 7, c = tid & 127;
    int NB = 1 << (2 * d);
    const float* Y = ws + YBASE_ + level_rel(d);
    int n = 4 * NB;
    float s = 0.f;
    for (int b = 0; b < 4; ++b)
        for (int k = 0; k < NB; ++k) s += Y[((size_t)b * 128 + c) * NB + k];
    float mean = s / (float)n;
    float v = 0.f;
    for (int b = 0; b < 4; ++b)
        for (int k = 0; k < NB; ++k) {
            float dd = Y[((size_t)b * 128 + c) * NB + k] - mean;
            v = fmaf(dd, dd, v);
        }
    float var = v / (float)n;
    float sc = conv_g[d * 128 + c] * rsqrtf(var + 1e-5f);
    ws[SCALED_OFF + tid] = sc;
    ws[SHIFTD_OFF + tid] = conv_b[d * 128 + c] - mean * sc;
}

// K3c: contrib[b][o][blk3] = sum_{d,c} pnorm_d[b,c,parent_d(blk3)] * final_w[o][128 + d*128 + c]
// grid = B*64, block 128 (thread = o)
__global__ __launch_bounds__(128) void k_contrib(const float* __restrict__ final_w,
                                                 float* __restrict__ ws) {
    int b = blockIdx.x >> 6, blk3 = blockIdx.x & 63;
    int i3 = blk3 >> 3, j3 = blk3 & 7;
    __shared__ float pn[512];
    int t = threadIdx.x;
    for (int k = t; k < 512; k += 128) {
        int d = k >> 7, c = k & 127;
        int sh = 3 - d;
        int blkd = (i3 >> sh) * (1 << d) + (j3 >> sh);
        int NB = 1 << (2 * d);
        float yv = ws[YBASE_ + level_rel(d) + ((size_t)b * 128 + c) * NB + blkd];
        pn[k] = yv * ws[SCALED_OFF + k] + ws[SHIFTD_OFF + k];
    }
    __syncthreads();
    const float* fw = final_w + (size_t)t * 640 + 128;
    float acc = 0.f;
#pragma unroll 8
    for (int k = 0; k < 512; k += 4) {
        float4 f = *(const float4*)(fw + k);
        acc = fmaf(pn[k], f.x, acc);
        acc = fmaf(pn[k + 1], f.y, acc);
        acc = fmaf(pn[k + 2], f.z, acc);
        acc = fmaf(pn[k + 3], f.w, acc);
    }
    ws[CONTRIB_OFF + ((size_t)b * 128 + t) * 64 + blk3] = acc;
}

// K5: z[b,o,p] = sum_c x[b,c,p]*W0t[c][o] + contrib[b,o,blk3] ; write z to out,
// reduce per-WG per-o sum/sumsq to ws partials (deterministic shuffle reduce).
// grid = B * 1024(ptile) * 2(otile), block 256. Tile: 64 p x 64 o, K=128.
__global__ __launch_bounds__(256) void k_gemm(const float* __restrict__ x,
                                              float* __restrict__ ws,
                                              float* __restrict__ out) {
    __shared__ float xs[8192];   // [c][64 p]
    __shared__ float wls[8192];  // [c][64 o]
    int wg = blockIdx.x;
    int ot = wg & 1;
    int pt = (wg >> 1) & 1023;
    int b = wg >> 11;
    int p0 = pt * 64, o0 = ot * 64;
    int t = threadIdx.x;
    const float* xb = x + (size_t)b * C_ * P_;
#pragma unroll
    for (int i = 0; i < 8; ++i) {
        int qd = i * 256 + t;        // quad 0..2047
        int c = qd >> 4, qq = qd & 15;
        *(float4*)(&xs[c * 64 + qq * 4]) =
            *(const float4*)(xb + (size_t)c * P_ + p0 + qq * 4);
        *(float4*)(&wls[c * 64 + qq * 4]) =
            *(const float4*)(ws + W0T_OFF + c * 128 + o0 + qq * 4);
    }
    __syncthreads();
    int wo = t >> 4, wp = t & 15;   // o-quad 0..15, p-quad 0..15
    float acc[4][4] = {{0.f}};
    for (int c = 0; c < 128; ++c) {
        float wv[4], xv[4];
        *(float4*)wv = *(const float4*)(&wls[c * 64 + wo * 4]);
        *(float4*)xv = *(const float4*)(&xs[c * 64 + wp * 4]);
#pragma unroll
        for (int j = 0; j < 4; ++j)
#pragma unroll
            for (int i = 0; i < 4; ++i) acc[j][i] = fmaf(wv[j], xv[i], acc[j][i]);
    }
    __syncthreads();  // done reading xs/wls; reuse xs for reductions
    float* reds = xs;
    float* redss = xs + 64;
    int h = p0 >> 8;
    int wcol = (p0 & 255) + wp * 4;
    int blk3 = (h >> 5) * 8 + (wcol >> 5);
#pragma unroll
    for (int j = 0; j < 4; ++j) {
        int o = o0 + wo * 4 + j;
        float cv = ws[CONTRIB_OFF + ((size_t)b * 128 + o) * 64 + blk3];
        float4 z;
        z.x = acc[j][0] + cv;
        z.y = acc[j][1] + cv;
        z.z = acc[j][2] + cv;
        z.w = acc[j][3] + cv;
        *(float4*)(out + ((size_t)b * 128 + o) * (size_t)P_ + p0 + wp * 4) = z;
        float s = (z.x + z.y) + (z.z + z.w);
        float ss = fmaf(z.x, z.x, fmaf(z.y, z.y, fmaf(z.z, z.z, z.w * z.w)));
        // reduce over the 16 wp lanes (contiguous lanes within the wave)
#pragma unroll
        for (int k = 1; k < 16; k <<= 1) {
            s += __shfl_xor(s, k);
            ss += __shfl_xor(ss, k);
        }
        if (wp == 0) {
            reds[wo * 4 + j] = s;
            redss[wo * 4 + j] = ss;
        }
    }
    __syncthreads();
    if (t < 64) {
        int o = o0 + t;
        int wg_po = b * 1024 + pt;
        ws[PSUM_OFF + (size_t)o * 4096 + wg_po] = reds[t];
        ws[PSS_OFF + (size_t)o * 4096 + wg_po] = redss[t];
    }
}

// K6: reduce partials -> final BN scale/shift per o. grid = 128, block 256
__global__ __launch_bounds__(256) void k_bnstats_f(const float* __restrict__ final_g,
                                                   const float* __restrict__ final_b,
                                                   float* __restrict__ ws) {
    int o = blockIdx.x;
    int t = threadIdx.x;
    float s = 0.f, ss = 0.f;
    for (int i = t; i < 4096; i += 256) {
        s += ws[PSUM_OFF + (size_t)o * 4096 + i];
        ss += ws[PSS_OFF + (size_t)o * 4096 + i];
    }
#pragma unroll
    for (int k = 1; k < 64; k <<= 1) {
        s += __shfl_xor(s, k);
        ss += __shfl_xor(ss, k);
    }
    __shared__ float rs[4], rss[4];
    int lane = t & 63, w = t >> 6;
    if (lane == 0) { rs[w] = s; rss[w] = ss; }
    __syncthreads();
    if (t == 0) {
        float S = (rs[0] + rs[1]) + (rs[2] + rs[3]);
        float SS = (rss[0] + rss[1]) + (rss[2] + rss[3]);
        float mean = S / 262144.f;
        float var = SS / 262144.f - mean * mean;
        float sc = final_g[o] * rsqrtf(var + 1e-5f);
        ws[SCALEF_OFF + o] = sc;
        ws[SHIFTF_OFF + o] = final_b[o] - mean * sc;
    }
}

// K7: normalize out in place. 8M float4
__global__ __launch_bounds__(256) void k_norm(float* __restrict__ out,
                                              const float* __restrict__ ws) {
    size_t stride = (size_t)gridDim.x * 256;
    for (size_t i = (size_t)blockIdx.x * 256 + threadIdx.x; i < 8388608; i += stride) {
        int o = (int)((i >> 14) & 127);
        float sc = ws[SCALEF_OFF + o], sh = ws[SHIFTF_OFF + o];
        float4 v = *(float4*)(out + i * 4);
        v.x = fmaf(v.x, sc, sh);
        v.y = fmaf(v.y, sc, sh);
        v.z = fmaf(v.z, sc, sh);
        v.w = fmaf(v.w, sc, sh);
        *(float4*)(out + i * 4) = v;
    }
}

extern "C" void kernel_launch(void* const* d_in, const int* in_sizes, int n_in,
                              void* d_out, int out_size, void* d_ws, size_t ws_size,
                              hipStream_t stream) {
    const float* x = (const float*)d_in[0];
    const float* conv_w = (const float*)d_in[1];
    const float* conv_g = (const float*)d_in[2];
    const float* conv_b = (const float*)d_in[3];
    const float* final_w = (const float*)d_in[4];
    const float* final_g = (const float*)d_in[5];
    const float* final_b = (const float*)d_in[6];
    float* out = (float*)d_out;
    float* ws = (float*)d_ws;

    k_w0t<<<64, 256, 0, stream>>>(final_w, ws);
    k_blockmax<<<B_ * C_ * 8, 256, 0, stream>>>(x, ws);
    k_levels<<<2, 256, 0, stream>>>(ws);
    k_conv_pool<<<64, 256, 0, stream>>>(conv_w, ws);
    k_bnstats_d<<<2, 256, 0, stream>>>(conv_g, conv_b, ws);
    k_contrib<<<B_ * 64, 128, 0, stream>>>(final_w, ws);
    k_gemm<<<B_ * 1024 * 2, 256, 0, stream>>>(x, ws, out);
    k_bnstats_f<<<128, 256, 0, stream>>>(final_g, final_b, ws);
    k_norm<<<2048, 256, 0, stream>>>(out, ws);
}

// Round 2
// 269.616 us; speedup vs baseline: 1.1257x; 1.1257x over previous
//
#include <hip/hip_runtime.h>
#include <hip/hip_bf16.h>
#include <math.h>

// Problem dims (hardcoded to reference setup)
// x: [4,128,256,256] f32; conv_w: [4,128,128]; conv_g/b: [4,128]
// final_w: [128,640]; final_g/b: [128]; out: [4,128,256,256] f32
#define B_ 4
#define C_ 128
#define P_ 65536
#define NCH 512  // B_*C_

// ---- workspace float offsets ----
// M levels (block maxima): M3[512][64]@0, M2@32768, M1@40960, M0@43008
#define YBASE_      43520   // y levels, same internal layout as M
#define SCALED_OFF  87040   // [4][128] per-branch BN scale
#define SHIFTD_OFF  87552   // [4][128] per-branch BN shift
#define CONTRIB_OFF 88064   // [B][C][64]
#define WARR_OFF    120832  // [16 oblk][128 k][8 o] rearranged final_w block 0
#define PSUM_OFF    137216  // [128 o][512 ptile]
#define PSS_OFF     202752  // [128 o][512 ptile]
#define SCALEF_OFF  268288  // [128]
#define SHIFTF_OFF  268416  // [128]
// total floats: 268544 (~1.05 MB)

typedef float float8_t __attribute__((ext_vector_type(8)));

__device__ __forceinline__ int level_rel(int d) {
    return YBASE_ - 512 * (((1 << (2 * (d + 1))) - 1) / 3);
}

#define GLDS16(src, dst)                                                    \
    __builtin_amdgcn_global_load_lds(                                       \
        (const __attribute__((address_space(1))) unsigned int*)(src),       \
        (__attribute__((address_space(3))) unsigned int*)(dst), 16, 0, 0)

// K0: rearrange final_w block-0 -> Warr[oblk][k][8]
__global__ __launch_bounds__(256) void k_wprep(const float* __restrict__ final_w,
                                               float* __restrict__ ws) {
    int idx = blockIdx.x * 256 + threadIdx.x;  // 16384
    if (idx >= 16384) return;
    int ob = idx >> 10, rem = idx & 1023;
    int k = rem >> 3, j = rem & 7;
    ws[WARR_OFF + idx] = final_w[(size_t)(ob * 8 + j) * 640 + k];
}

// K1: 32x32 block maxima + all pyramid levels. grid = B*C (one WG per (b,c))
__global__ __launch_bounds__(256) void k_blockmax(const float* __restrict__ x,
                                                  float* __restrict__ ws) {
    int bc = blockIdx.x;  // 512
    const float* xp = x + (size_t)bc * P_;
    int t = threadIdx.x, lane = t & 63, wv = t >> 6;
    __shared__ float red[32];  // [4 wave][8 colblk]
    __shared__ float bm[64];   // M3 of this (b,c)
    __shared__ float lv[24];   // m2[16], m1[4], spare
    for (int br = 0; br < 8; ++br) {
        float m = -3.402823466e38f;
#pragma unroll
        for (int it = 0; it < 8; ++it) {
            int h = br * 32 + it * 4 + wv;
            float4 v = *(const float4*)(xp + (size_t)h * 256 + lane * 4);
            m = fmaxf(m, fmaxf(fmaxf(v.x, v.y), fmaxf(v.z, v.w)));
        }
        // reduce within 8-lane group (shared column block)
        m = fmaxf(m, __shfl_xor(m, 1));
        m = fmaxf(m, __shfl_xor(m, 2));
        m = fmaxf(m, __shfl_xor(m, 4));
        if ((lane & 7) == 0) red[wv * 8 + (lane >> 3)] = m;
        __syncthreads();
        if (t < 8) {
            float mm = fmaxf(fmaxf(red[t], red[8 + t]), fmaxf(red[16 + t], red[24 + t]));
            bm[br * 8 + t] = mm;
            ws[(size_t)bc * 64 + br * 8 + t] = mm;  // M3
        }
        __syncthreads();
    }
    // M2
    if (t < 16) {
        int i2 = t >> 2, j2 = t & 3;
        float m = -3.402823466e38f;
        for (int a = 0; a < 2; ++a)
            for (int b2 = 0; b2 < 2; ++b2)
                m = fmaxf(m, bm[(2 * i2 + a) * 8 + 2 * j2 + b2]);
        lv[t] = m;
        ws[32768 + (size_t)bc * 16 + t] = m;
    }
    __syncthreads();
    // M1
    if (t < 4) {
        int i1 = t >> 1, j1 = t & 1;
        float m = -3.402823466e38f;
        for (int a = 0; a < 2; ++a)
            for (int b2 = 0; b2 < 2; ++b2)
                m = fmaxf(m, lv[(2 * i1 + a) * 4 + 2 * j1 + b2]);
        lv[16 + t] = m;
        ws[40960 + (size_t)bc * 4 + t] = m;
    }
    __syncthreads();
    // M0
    if (t == 0) {
        ws[43008 + bc] = fmaxf(fmaxf(lv[16], lv[17]), fmaxf(lv[18], lv[19]));
    }
}

// K3a: y_d[b,co,blk] = sum_ci M_d[b,ci,blk] * conv_w[d][co][ci]
// grid = 4(d) * 4(b) * 4(co-chunk of 32), block 256
__global__ __launch_bounds__(256) void k_conv_pool(const float* __restrict__ conv_w,
                                                   float* __restrict__ ws) {
    int bid = blockIdx.x;
    int d = bid >> 4, b = (bid >> 2) & 3, cchunk = bid & 3;
    int NB = 1 << (2 * d);
    int rel = level_rel(d);
    const float* Mb = ws + rel + (size_t)b * 128 * NB;
    float* Yb = ws + YBASE_ + rel + (size_t)b * 128 * NB;
    __shared__ float mlds[8192];
    int t = threadIdx.x;
    int tot = 128 * NB;
    for (int i = t; i < tot; i += 256) mlds[i] = Mb[i];
    __syncthreads();
    if (NB >= 4) {
        int nbq = NB >> 2;
        int nq = 32 * nbq;
        for (int qi = t; qi < nq; qi += 256) {
            int co = cchunk * 32 + (qi >> (2 * d - 2));
            int bq = qi & (nbq - 1);
            const float* wrow = conv_w + ((size_t)d * 128 + co) * 128;
            float a0 = 0.f, a1 = 0.f, a2 = 0.f, a3 = 0.f;
            for (int ci = 0; ci < 128; ++ci) {
                float4 mv = *(const float4*)(&mlds[ci * NB + bq * 4]);
                float wvv = wrow[ci];
                a0 = fmaf(wvv, mv.x, a0);
                a1 = fmaf(wvv, mv.y, a1);
                a2 = fmaf(wvv, mv.z, a2);
                a3 = fmaf(wvv, mv.w, a3);
            }
            float4 r;
            r.x = a0; r.y = a1; r.z = a2; r.w = a3;
            *(float4*)(&Yb[co * NB + bq * 4]) = r;
        }
    } else {  // d == 0
        for (int oi = t; oi < 32; oi += 256) {
            int co = cchunk * 32 + oi;
            const float* wrow = conv_w + (size_t)co * 128;
            float acc = 0.f;
            for (int ci = 0; ci < 128; ++ci) acc = fmaf(mlds[ci], wrow[ci], acc);
            Yb[co] = acc;
        }
    }
}

// K3b: per-(d,c) BN stats over (b,blk) -> scale/shift
__global__ __launch_bounds__(256) void k_bnstats_d(const float* __restrict__ conv_g,
                                                   const float* __restrict__ conv_b,
                                                   float* __restrict__ ws) {
    int tid = blockIdx.x * 256 + threadIdx.x;
    if (tid >= 512) return;
    int d = tid >> 7, c = tid & 127;
    int NB = 1 << (2 * d);
    const float* Y = ws + YBASE_ + level_rel(d);
    int n = 4 * NB;
    float s = 0.f;
    for (int b = 0; b < 4; ++b)
        for (int k = 0; k < NB; ++k) s += Y[((size_t)b * 128 + c) * NB + k];
    float mean = s / (float)n;
    float v = 0.f;
    for (int b = 0; b < 4; ++b)
        for (int k = 0; k < NB; ++k) {
            float dd = Y[((size_t)b * 128 + c) * NB + k] - mean;
            v = fmaf(dd, dd, v);
        }
    float var = v / (float)n;
    float sc = conv_g[d * 128 + c] * rsqrtf(var + 1e-5f);
    ws[SCALED_OFF + tid] = sc;
    ws[SHIFTD_OFF + tid] = conv_b[d * 128 + c] - mean * sc;
}

// K3c: contrib[b][o][blk3]. grid = B*64, block 128 (thread = o)
__global__ __launch_bounds__(128) void k_contrib(const float* __restrict__ final_w,
                                                 float* __restrict__ ws) {
    int b = blockIdx.x >> 6, blk3 = blockIdx.x & 63;
    int i3 = blk3 >> 3, j3 = blk3 & 7;
    __shared__ float pn[512];
    int t = threadIdx.x;
    for (int k = t; k < 512; k += 128) {
        int d = k >> 7, c = k & 127;
        int sh = 3 - d;
        int blkd = (i3 >> sh) * (1 << d) + (j3 >> sh);
        int NB = 1 << (2 * d);
        float yv = ws[YBASE_ + level_rel(d) + ((size_t)b * 128 + c) * NB + blkd];
        pn[k] = yv * ws[SCALED_OFF + k] + ws[SHIFTD_OFF + k];
    }
    __syncthreads();
    const float* fw = final_w + (size_t)t * 640 + 128;
    float acc = 0.f;
#pragma unroll 8
    for (int k = 0; k < 512; k += 4) {
        float4 f = *(const float4*)(fw + k);
        acc = fmaf(pn[k], f.x, acc);
        acc = fmaf(pn[k + 1], f.y, acc);
        acc = fmaf(pn[k + 2], f.z, acc);
        acc = fmaf(pn[k + 3], f.w, acc);
    }
    ws[CONTRIB_OFF + ((size_t)b * 128 + t) * 64 + blk3] = acc;
}

// K5: z[b,o,p] = sum_c x[b,c,p]*W0[o,c] + contrib[b,o,blk3]; write z,
// accumulate per-(o, p-tile) partial sum/sumsq.
// grid = 4(ogroup) * 512(ptile-global), block 256 = 4 waves.
// Wave = one 8-o block (W via uniform scalar loads), thread = 8 px x 8 o.
__global__ __launch_bounds__(256, 4) void k_gemm(
    const float* __restrict__ x, const float* __restrict__ Warr,
    const float* __restrict__ contrib, float* __restrict__ psum,
    float* __restrict__ pss, float* __restrict__ out) {
    __shared__ float xls[8192];  // [16 c][512 p] fp32, 32 KB
    int bid = blockIdx.x;
    int og = bid >> 9;      // 0..3 (o group of 32)
    int ptg = bid & 511;    // global p-tile
    int b = ptg >> 7;
    int p0 = (ptg & 127) * 512;
    int t = threadIdx.x, lane = t & 63;
    int wv = __builtin_amdgcn_readfirstlane(t >> 6);
    const float* xb = x + (size_t)b * C_ * P_;
    const float* Wp = Warr + (size_t)(og * 4 + wv) * 1024;

    float4 acc[8][2];
#pragma unroll
    for (int j = 0; j < 8; ++j) {
        acc[j][0] = make_float4(0.f, 0.f, 0.f, 0.f);
        acc[j][1] = make_float4(0.f, 0.f, 0.f, 0.f);
    }

    for (int ch = 0; ch < 8; ++ch) {
        // stage x[ch*16 .. +16][p0 .. p0+512] into LDS; wave wv does 4 rows
#pragma unroll
        for (int r = 0; r < 4; ++r) {
            int cl = wv * 4 + r;
            const float* src = xb + (size_t)(ch * 16 + cl) * P_ + p0 + lane * 4;
            GLDS16(src, &xls[cl * 512]);
            GLDS16(src + 256, &xls[cl * 512 + 256]);
        }
        __syncthreads();
#pragma unroll
        for (int k = 0; k < 16; ++k) {
            float8_t wf = *(const float8_t*)(Wp + (size_t)(ch * 16 + k) * 8);
            float4 xa = *(const float4*)(&xls[k * 512 + lane * 4]);
            float4 xc = *(const float4*)(&xls[k * 512 + 256 + lane * 4]);
#pragma unroll
            for (int j = 0; j < 8; ++j) {
                float w = wf[j];
                acc[j][0].x = fmaf(w, xa.x, acc[j][0].x);
                acc[j][0].y = fmaf(w, xa.y, acc[j][0].y);
                acc[j][0].z = fmaf(w, xa.z, acc[j][0].z);
                acc[j][0].w = fmaf(w, xa.w, acc[j][0].w);
                acc[j][1].x = fmaf(w, xc.x, acc[j][1].x);
                acc[j][1].y = fmaf(w, xc.y, acc[j][1].y);
                acc[j][1].z = fmaf(w, xc.z, acc[j][1].z);
                acc[j][1].w = fmaf(w, xc.w, acc[j][1].w);
            }
        }
        __syncthreads();
    }

    // epilogue: add contrib, store z, partial stats
    int h0 = p0 >> 8;                              // image row of first 256 px
    int cvi = (h0 >> 5) * 8 + (lane >> 3);         // blk3 index (same for both rows)
    int obase = og * 32 + wv * 8;
#pragma unroll
    for (int j = 0; j < 8; ++j) {
        int o = obase + j;
        float cv = contrib[((size_t)(b * 128 + o)) * 64 + cvi];
        float4 z0 = acc[j][0], z1 = acc[j][1];
        z0.x += cv; z0.y += cv; z0.z += cv; z0.w += cv;
        z1.x += cv; z1.y += cv; z1.z += cv; z1.w += cv;
        float* op = out + ((size_t)(b * 128 + o)) * P_ + p0 + lane * 4;
        *(float4*)op = z0;
        *(float4*)(op + 256) = z1;
        float ls = ((z0.x + z0.y) + (z0.z + z0.w)) + ((z1.x + z1.y) + (z1.z + z1.w));
        float lq = fmaf(z0.x, z0.x, fmaf(z0.y, z0.y, fmaf(z0.z, z0.z, z0.w * z0.w)));
        lq = fmaf(z1.x, z1.x, fmaf(z1.y, z1.y, fmaf(z1.z, z1.z, fmaf(z1.w, z1.w, lq))));
#pragma unroll
        for (int k2 = 1; k2 < 64; k2 <<= 1) {
            ls += __shfl_xor(ls, k2);
            lq += __shfl_xor(lq, k2);
        }
        if (lane == 0) {
            psum[(size_t)o * 512 + ptg] = ls;
            pss[(size_t)o * 512 + ptg] = lq;
        }
    }
}

// K6: reduce partials -> final BN scale/shift. grid = 128, block 256
__global__ __launch_bounds__(256) void k_bnstats_f(const float* __restrict__ final_g,
                                                   const float* __restrict__ final_b,
                                                   float* __restrict__ ws) {
    int o = blockIdx.x;
    int t = threadIdx.x;
    float s = 0.f, ss = 0.f;
    for (int i = t; i < 512; i += 256) {
        s += ws[PSUM_OFF + (size_t)o * 512 + i];
        ss += ws[PSS_OFF + (size_t)o * 512 + i];
    }
#pragma unroll
    for (int k = 1; k < 64; k <<= 1) {
        s += __shfl_xor(s, k);
        ss += __shfl_xor(ss, k);
    }
    __shared__ float rs[4], rss[4];
    int lane = t & 63, w = t >> 6;
    if (lane == 0) { rs[w] = s; rss[w] = ss; }
    __syncthreads();
    if (t == 0) {
        float S = (rs[0] + rs[1]) + (rs[2] + rs[3]);
        float SS = (rss[0] + rss[1]) + (rss[2] + rss[3]);
        float mean = S / 262144.f;
        float var = SS / 262144.f - mean * mean;
        float sc = final_g[o] * rsqrtf(var + 1e-5f);
        ws[SCALEF_OFF + o] = sc;
        ws[SHIFTF_OFF + o] = final_b[o] - mean * sc;
    }
}

// K7: normalize out in place. 8.4M float4
__global__ __launch_bounds__(256) void k_norm(float* __restrict__ out,
                                              const float* __restrict__ ws) {
    size_t stride = (size_t)gridDim.x * 256;
    for (size_t i = (size_t)blockIdx.x * 256 + threadIdx.x; i < 8388608; i += stride) {
        int o = (int)((i >> 14) & 127);
        float sc = ws[SCALEF_OFF + o], sh = ws[SHIFTF_OFF + o];
        float4 v = *(float4*)(out + i * 4);
        v.x = fmaf(v.x, sc, sh);
        v.y = fmaf(v.y, sc, sh);
        v.z = fmaf(v.z, sc, sh);
        v.w = fmaf(v.w, sc, sh);
        *(float4*)(out + i * 4) = v;
    }
}

extern "C" void kernel_launch(void* const* d_in, const int* in_sizes, int n_in,
                              void* d_out, int out_size, void* d_ws, size_t ws_size,
                              hipStream_t stream) {
    const float* x = (const float*)d_in[0];
    const float* conv_w = (const float*)d_in[1];
    const float* conv_g = (const float*)d_in[2];
    const float* conv_b = (const float*)d_in[3];
    const float* final_w = (const float*)d_in[4];
    const float* final_g = (const float*)d_in[5];
    const float* final_b = (const float*)d_in[6];
    float* out = (float*)d_out;
    float* ws = (float*)d_ws;

    k_wprep<<<64, 256, 0, stream>>>(final_w, ws);
    k_blockmax<<<NCH, 256, 0, stream>>>(x, ws);
    k_conv_pool<<<64, 256, 0, stream>>>(conv_w, ws);
    k_bnstats_d<<<2, 256, 0, stream>>>(conv_g, conv_b, ws);
    k_contrib<<<B_ * 64, 128, 0, stream>>>(final_w, ws);
    k_gemm<<<4 * 512, 256, 0, stream>>>(x, ws + WARR_OFF, ws + CONTRIB_OFF,
                                        ws + PSUM_OFF, ws + PSS_OFF, out);
    k_bnstats_f<<<128, 256, 0, stream>>>(final_g, final_b, ws);
    k_norm<<<2048, 256, 0, stream>>>(out, ws);
}

// Round 4
// 204.777 us; speedup vs baseline: 1.4822x; 1.3166x over previous
//
#include <hip/hip_runtime.h>
#include <hip/hip_bf16.h>
#include <math.h>
#include <float.h>

// x: [4,128,256,256] f32; conv_w: [4,128,128]; conv_g/b: [4,128]
// final_w: [128,640]; final_g/b: [128]; out: [4,128,256,256] f32
#define B_ 4
#define C_ 128
#define P_ 65536

// ---- workspace float offsets ----
#define M3_OFF      0        // [512][64] block maxima (32x32), exact fp32
#define M2_OFF      32768    // [512][16]
#define M1_OFF      40960    // [512][4]
#define M0_OFF      43008    // [512]
#define YBASE_      43520    // y levels, same internal layout as M
#define SCALED_OFF  87040    // [4][128]
#define SHIFTD_OFF  87552    // [4][128]
#define CONTRIB_OFF 88064    // [4][128][64]
#define S3_OFF      120832   // [512][64] block sums (32x32), exact fp32
#define SX_OFF      153600   // [512] per-(b,c) total sum
#define G_OFF       154112   // [4][128][128] Gram (bf16-sourced, fp32 accum)
#define SCALEF_OFF  219648   // [128]
#define SHIFTF_OFF  219776   // [128]
// total floats: 219904 (~0.84 MB)

using short8 = __attribute__((ext_vector_type(8))) short;
using f32x4 = __attribute__((ext_vector_type(4))) float;

__device__ __forceinline__ int level_rel(int d) {
    return YBASE_ - 512 * (((1 << (2 * (d + 1))) - 1) / 3);
}

// RNE pack of two f32 into bf16x2 (low = first arg)
__device__ __forceinline__ unsigned int bfpair(float a, float b) {
    unsigned int ua = __float_as_uint(a), ub = __float_as_uint(b);
    ua = (ua + 0x7fffu + ((ua >> 16) & 1u)) >> 16;
    ub = (ub + 0x7fffu + ((ub >> 16) & 1u)) & 0xffff0000u;
    return ua | ub;
}

// K1: exact fp32 32x32 block max + sum, full pyramid. grid = 512 (b,c), block 256
__global__ __launch_bounds__(256) void k_blockmax(const float* __restrict__ x,
                                                  float* __restrict__ ws) {
    int bc = blockIdx.x;  // 512
    const float* xp = x + (size_t)bc * P_;
    int t = threadIdx.x, lane = t & 63, wv = t >> 6;
    __shared__ float redm[32], reds[32];  // [4 wave][8 colblk]
    __shared__ float bm[64], bs[64];      // M3 / S3 of this (b,c)
    __shared__ float lv[24];              // m2[16], m1[4]
    for (int br = 0; br < 8; ++br) {
        float m = -FLT_MAX, s = 0.f;
#pragma unroll
        for (int it = 0; it < 8; ++it) {
            int h = br * 32 + it * 4 + wv;
            float4 v = *(const float4*)(xp + (size_t)h * 256 + lane * 4);
            m = fmaxf(m, fmaxf(fmaxf(v.x, v.y), fmaxf(v.z, v.w)));
            s += ((v.x + v.y) + (v.z + v.w));
        }
        // reduce within 8-lane group (one 32-px column block)
        m = fmaxf(m, __shfl_xor(m, 1)); s += __shfl_xor(s, 1);
        m = fmaxf(m, __shfl_xor(m, 2)); s += __shfl_xor(s, 2);
        m = fmaxf(m, __shfl_xor(m, 4)); s += __shfl_xor(s, 4);
        if ((lane & 7) == 0) {
            redm[wv * 8 + (lane >> 3)] = m;
            reds[wv * 8 + (lane >> 3)] = s;
        }
        __syncthreads();
        if (t < 8) {
            float mm = fmaxf(fmaxf(redm[t], redm[8 + t]), fmaxf(redm[16 + t], redm[24 + t]));
            float ss = (reds[t] + reds[8 + t]) + (reds[16 + t] + reds[24 + t]);
            bm[br * 8 + t] = mm;
            bs[br * 8 + t] = ss;
            ws[M3_OFF + (size_t)bc * 64 + br * 8 + t] = mm;
            ws[S3_OFF + (size_t)bc * 64 + br * 8 + t] = ss;
        }
        __syncthreads();
    }
    // SX
    if (t < 8) {
        float sx = 0.f;
        for (int r = 0; r < 8; ++r) sx += bs[t * 8 + r];
        reds[t] = sx;
    }
    // M2
    if (t < 16) {
        int i2 = t >> 2, j2 = t & 3;
        float m = -FLT_MAX;
        for (int a = 0; a < 2; ++a)
            for (int b2 = 0; b2 < 2; ++b2)
                m = fmaxf(m, bm[(2 * i2 + a) * 8 + 2 * j2 + b2]);
        lv[t] = m;
        ws[M2_OFF + (size_t)bc * 16 + t] = m;
    }
    __syncthreads();
    if (t == 0) {
        float sx = 0.f;
        for (int r = 0; r < 8; ++r) sx += reds[r];
        ws[SX_OFF + bc] = sx;
    }
    // M1
    if (t < 4) {
        int i1 = t >> 1, j1 = t & 1;
        float m = -FLT_MAX;
        for (int a = 0; a < 2; ++a)
            for (int b2 = 0; b2 < 2; ++b2)
                m = fmaxf(m, lv[(2 * i1 + a) * 4 + 2 * j1 + b2]);
        lv[16 + t] = m;
        ws[M1_OFF + (size_t)bc * 4 + t] = m;
    }
    __syncthreads();
    // M0
    if (t == 0)
        ws[M0_OFF + bc] = fmaxf(fmaxf(lv[16], lv[17]), fmaxf(lv[18], lv[19]));
}

// K2: per-(b, 2-row chunk) bf16 Gram partials via MFMA. grid = 512, block 256
__global__ __launch_bounds__(256) void k_gram(const float* __restrict__ x,
                                              float* __restrict__ gpart) {
    __shared__ uint4 tileq[2048];  // [128 c][128 p] bf16, XOR-swizzled, 32KB
    unsigned char* tile = (unsigned char*)tileq;
    int wg = blockIdx.x;
    int b = wg >> 7, rc = wg & 127;
    const float* xb = x + (size_t)b * C_ * P_ + (size_t)rc * 512;
    int t = threadIdx.x, l = t & 63, wv = t >> 6;
    int pq = t & 31, ci = t >> 5;

    f32x4 acc[2][8];
#pragma unroll
    for (int i = 0; i < 2; ++i)
#pragma unroll
        for (int j = 0; j < 8; ++j) acc[i][j] = (f32x4){0.f, 0.f, 0.f, 0.f};

    for (int s = 0; s < 4; ++s) {
        // stage: fp32 -> bf16 tile (coalesced loads, swizzled writes)
#pragma unroll
        for (int k = 0; k < 16; ++k) {
            int c = ci + 8 * k;
            float4 v = *(const float4*)(xb + (size_t)c * P_ + s * 128 + pq * 4);
            unsigned int u0 = bfpair(v.x, v.y), u1 = bfpair(v.z, v.w);
            int wa = (c * 256 + pq * 8) ^ ((c & 7) << 4);
            *(uint2*)(tile + wa) = make_uint2(u0, u1);
        }
        __syncthreads();
        // Gram MFMA: wave wv owns m-tiles {2wv, 2wv+1} x all 8 n-tiles
#pragma unroll
        for (int ks = 0; ks < 4; ++ks) {
            int col = ks * 64 + (l >> 4) * 16;
            int ra0 = (((2 * wv) * 16 + (l & 15)) * 256 + col) ^ ((l & 7) << 4);
            int ra1 = (((2 * wv + 1) * 16 + (l & 15)) * 256 + col) ^ ((l & 7) << 4);
            short8 a0 = *(const short8*)(tile + ra0);
            short8 a1 = *(const short8*)(tile + ra1);
#pragma unroll
            for (int nt = 0; nt < 8; ++nt) {
                int rb = ((nt * 16 + (l & 15)) * 256 + col) ^ ((l & 7) << 4);
                short8 bb = *(const short8*)(tile + rb);
                acc[0][nt] = __builtin_amdgcn_mfma_f32_16x16x32_bf16(a0, bb, acc[0][nt], 0, 0, 0);
                acc[1][nt] = __builtin_amdgcn_mfma_f32_16x16x32_bf16(a1, bb, acc[1][nt], 0, 0, 0);
            }
        }
        __syncthreads();
    }
    // write Gram partials to gpart[wg][128][128] (G is symmetric so any
    // row/col convention of the C/D layout is self-consistent)
    size_t gb = (size_t)wg * 16384;
#pragma unroll
    for (int mt2 = 0; mt2 < 2; ++mt2) {
        int mt = wv * 2 + mt2;
#pragma unroll
        for (int nt = 0; nt < 8; ++nt)
#pragma unroll
            for (int r = 0; r < 4; ++r)
                gpart[gb + (size_t)(mt * 16 + (l >> 4) * 4 + r) * 128 + nt * 16 + (l & 15)] =
                    acc[mt2][nt][r];
    }
}

// K2a: reduce Gram partials over 128 row-chunks per b. grid = 256, block 256
__global__ __launch_bounds__(256) void k_reduceG(const float* __restrict__ gpart,
                                                 float* __restrict__ ws) {
    int tid = blockIdx.x * 256 + threadIdx.x;  // 65536
    int b = tid >> 14, inner = tid & 16383;
    const float* p = gpart + (size_t)b * 128 * 16384 + inner;
    float s = 0.f;
    for (int r = 0; r < 128; ++r) s += p[(size_t)r * 16384];
    ws[G_OFF + tid] = s;
}

// K3a: y_d[b,co,blk] = sum_ci M_d[b,ci,blk] * conv_w[d][co][ci]
__global__ __launch_bounds__(256) void k_conv_pool(const float* __restrict__ conv_w,
                                                   float* __restrict__ ws) {
    int bid = blockIdx.x;
    int d = bid >> 4, b = (bid >> 2) & 3, cchunk = bid & 3;
    int NB = 1 << (2 * d);
    int rel = level_rel(d);
    const float* Mb = ws + rel + (size_t)b * 128 * NB;
    float* Yb = ws + YBASE_ + rel + (size_t)b * 128 * NB;
    __shared__ float mlds[8192];
    int t = threadIdx.x;
    int tot = 128 * NB;
    for (int i = t; i < tot; i += 256) mlds[i] = Mb[i];
    __syncthreads();
    if (NB >= 4) {
        int nbq = NB >> 2;
        int nq = 32 * nbq;
        for (int qi = t; qi < nq; qi += 256) {
            int co = cchunk * 32 + (qi >> (2 * d - 2));
            int bq = qi & (nbq - 1);
            const float* wrow = conv_w + ((size_t)d * 128 + co) * 128;
            float a0 = 0.f, a1 = 0.f, a2 = 0.f, a3 = 0.f;
            for (int ci = 0; ci < 128; ++ci) {
                float4 mv = *(const float4*)(&mlds[ci * NB + bq * 4]);
                float wvv = wrow[ci];
                a0 = fmaf(wvv, mv.x, a0);
                a1 = fmaf(wvv, mv.y, a1);
                a2 = fmaf(wvv, mv.z, a2);
                a3 = fmaf(wvv, mv.w, a3);
            }
            float4 r;
            r.x = a0; r.y = a1; r.z = a2; r.w = a3;
            *(float4*)(&Yb[co * NB + bq * 4]) = r;
        }
    } else {
        for (int oi = t; oi < 32; oi += 256) {
            int co = cchunk * 32 + oi;
            const float* wrow = conv_w + (size_t)co * 128;
            float acc = 0.f;
            for (int ci = 0; ci < 128; ++ci) acc = fmaf(mlds[ci], wrow[ci], acc);
            Yb[co] = acc;
        }
    }
}

// K3b: per-(d,c) BN stats
__global__ __launch_bounds__(256) void k_bnstats_d(const float* __restrict__ conv_g,
                                                   const float* __restrict__ conv_b,
                                                   float* __restrict__ ws) {
    int tid = blockIdx.x * 256 + threadIdx.x;
    if (tid >= 512) return;
    int d = tid >> 7, c = tid & 127;
    int NB = 1 << (2 * d);
    const float* Y = ws + YBASE_ + level_rel(d);
    int n = 4 * NB;
    float s = 0.f;
    for (int b = 0; b < 4; ++b)
        for (int k = 0; k < NB; ++k) s += Y[((size_t)b * 128 + c) * NB + k];
    float mean = s / (float)n;
    float v = 0.f;
    for (int b = 0; b < 4; ++b)
        for (int k = 0; k < NB; ++k) {
            float dd = Y[((size_t)b * 128 + c) * NB + k] - mean;
            v = fmaf(dd, dd, v);
        }
    float var = v / (float)n;
    float sc = conv_g[d * 128 + c] * rsqrtf(var + 1e-5f);
    ws[SCALED_OFF + tid] = sc;
    ws[SHIFTD_OFF + tid] = conv_b[d * 128 + c] - mean * sc;
}

// K3c: contrib[b][o][blk3]. grid = B*64, block 128 (thread = o)
__global__ __launch_bounds__(128) void k_contrib(const float* __restrict__ final_w,
                                                 float* __restrict__ ws) {
    int b = blockIdx.x >> 6, blk3 = blockIdx.x & 63;
    int i3 = blk3 >> 3, j3 = blk3 & 7;
    __shared__ float pn[512];
    int t = threadIdx.x;
    for (int k = t; k < 512; k += 128) {
        int d = k >> 7, c = k & 127;
        int sh = 3 - d;
        int blkd = (i3 >> sh) * (1 << d) + (j3 >> sh);
        int NB = 1 << (2 * d);
        float yv = ws[YBASE_ + level_rel(d) + ((size_t)b * 128 + c) * NB + blkd];
        pn[k] = yv * ws[SCALED_OFF + k] + ws[SHIFTD_OFF + k];
    }
    __syncthreads();
    const float* fw = final_w + (size_t)t * 640 + 128;
    float acc = 0.f;
#pragma unroll 8
    for (int k = 0; k < 512; k += 4) {
        float4 f = *(const float4*)(fw + k);
        acc = fmaf(pn[k], f.x, acc);
        acc = fmaf(pn[k + 1], f.y, acc);
        acc = fmaf(pn[k + 2], f.z, acc);
        acc = fmaf(pn[k + 3], f.w, acc);
    }
    ws[CONTRIB_OFF + ((size_t)b * 128 + t) * 64 + blk3] = acc;
}

// K4: closed-form final BN stats: sum(z^2) = wGw + 2*sum_blk cv*(w.S3) + 1024*sum cv^2
// grid = 128 (o), block 128 (t = c)
__global__ __launch_bounds__(128) void k_stats(const float* __restrict__ final_w,
                                               const float* __restrict__ final_g,
                                               const float* __restrict__ final_b,
                                               float* __restrict__ ws) {
    int o = blockIdx.x, t = threadIdx.x;
    __shared__ __align__(16) float wlds[128];
    __shared__ __align__(16) float cvl[64];
    __shared__ float rbuf[4];
    wlds[t] = final_w[(size_t)o * 640 + t];
    __syncthreads();
    float SSQ = 0.f, SUM = 0.f;
    for (int b = 0; b < 4; ++b) {
        if (t < 64) cvl[t] = ws[CONTRIB_OFF + (size_t)(b * 128 + o) * 64 + t];
        __syncthreads();
        const float* Gb = ws + G_OFF + (size_t)b * 16384 + (size_t)t * 128;
        float a1 = 0.f;
#pragma unroll 8
        for (int k = 0; k < 128; k += 4) {
            float4 g = *(const float4*)(Gb + k);
            float4 w = *(const float4*)(&wlds[k]);
            a1 = fmaf(g.x, w.x, fmaf(g.y, w.y, fmaf(g.z, w.z, fmaf(g.w, w.w, a1))));
        }
        const float* S3p = ws + S3_OFF + (size_t)(b * 128 + t) * 64;
        float a2 = 0.f;
#pragma unroll 8
        for (int k = 0; k < 64; k += 4) {
            float4 sv = *(const float4*)(S3p + k);
            float4 cv = *(const float4*)(&cvl[k]);
            a2 = fmaf(sv.x, cv.x, fmaf(sv.y, cv.y, fmaf(sv.z, cv.z, fmaf(sv.w, cv.w, a2))));
        }
        float r1 = (a1 + 2.f * a2) * wlds[t];
        float r2 = wlds[t] * ws[SX_OFF + b * 128 + t];
        if (t < 64) {
            r1 += 1024.f * cvl[t] * cvl[t];
            r2 += 1024.f * cvl[t];
        }
#pragma unroll
        for (int k = 1; k < 64; k <<= 1) {
            r1 += __shfl_xor(r1, k);
            r2 += __shfl_xor(r2, k);
        }
        if ((t & 63) == 0) {
            rbuf[(t >> 6) * 2] = r1;
            rbuf[(t >> 6) * 2 + 1] = r2;
        }
        __syncthreads();
        SSQ += rbuf[0] + rbuf[2];
        SUM += rbuf[1] + rbuf[3];
        __syncthreads();
    }
    if (t == 0) {
        float mean = SUM / 262144.f;
        float var = SSQ / 262144.f - mean * mean;
        float sc = final_g[o] * rsqrtf(var + 1e-5f);
        ws[SCALEF_OFF + o] = sc;
        ws[SHIFTF_OFF + o] = final_b[o] - mean * sc;
    }
}

// K5: out[b,o,p] = (MFMA(W0,x) + contrib) * scale[o] + shift[o].
// grid = 2048 (b*512 + ptile of 128), block 256 (4 waves; wave = 32 p)
__global__ __launch_bounds__(256) void k_out(const float* __restrict__ x,
                                             const float* __restrict__ final_w,
                                             const float* __restrict__ ws,
                                             float* __restrict__ out) {
    __shared__ uint4 wtileq[2048];  // [128 o][128 c] bf16, swizzled, 32KB
    __shared__ float scl[128], shf[128], cvs[512];
    unsigned char* wtile = (unsigned char*)wtileq;
    int wgid = blockIdx.x;
    int b = wgid >> 9, pt = wgid & 511;
    int p0 = pt * 128;
    int t = threadIdx.x, l = t & 63, wv = t >> 6;
    // stage W0 (cols 0..127 of final_w) as bf16 [o][c]
#pragma unroll
    for (int it = 0; it < 32; ++it) {
        int pid = it * 256 + t;  // 8192 pairs
        int o = pid >> 6, cp = (pid & 63) * 2;
        float2 f = *(const float2*)(final_w + (size_t)o * 640 + cp);
        unsigned int u = bfpair(f.x, f.y);
        int wa = (o * 256 + cp * 2) ^ ((o & 7) << 4);
        *(unsigned int*)(wtile + wa) = u;
    }
    if (t < 128) {
        scl[t] = ws[SCALEF_OFF + t];
        shf[t] = ws[SHIFTF_OFF + t];
    }
    int i3 = pt >> 6, jb = (pt & 1) * 4;
    for (int q = t; q < 512; q += 256) {
        int o = q >> 2, jj = q & 3;
        cvs[q] = ws[CONTRIB_OFF + (size_t)(b * 128 + o) * 64 + i3 * 8 + jb + jj];
    }
    __syncthreads();

    const float* xb = x + (size_t)b * C_ * P_;
    int pw = p0 + wv * 32;
    f32x4 acc[8][2];
#pragma unroll
    for (int i = 0; i < 8; ++i) {
        acc[i][0] = (f32x4){0.f, 0.f, 0.f, 0.f};
        acc[i][1] = (f32x4){0.f, 0.f, 0.f, 0.f};
    }
#pragma unroll
    for (int ks = 0; ks < 4; ++ks) {
        short8 bf[2];
#pragma unroll
        for (int nt = 0; nt < 2; ++nt) {
            const float* xp = xb + (size_t)(ks * 32 + (l >> 4) * 8) * P_ + (pw + nt * 16 + (l & 15));
            float f0 = xp[0 * P_], f1 = xp[1 * P_], f2 = xp[2 * P_], f3 = xp[3 * P_];
            float f4 = xp[4 * P_], f5 = xp[5 * P_], f6 = xp[6 * P_], f7 = xp[7 * P_];
            union { uint4 u; short8 s; } cvtu;
            cvtu.u = make_uint4(bfpair(f0, f1), bfpair(f2, f3), bfpair(f4, f5), bfpair(f6, f7));
            bf[nt] = cvtu.s;
        }
#pragma unroll
        for (int mt = 0; mt < 8; ++mt) {
            int ra = ((mt * 16 + (l & 15)) * 256 + ks * 64 + (l >> 4) * 16) ^ ((l & 7) << 4);
            short8 af = *(const short8*)(wtile + ra);
            acc[mt][0] = __builtin_amdgcn_mfma_f32_16x16x32_bf16(af, bf[0], acc[mt][0], 0, 0, 0);
            acc[mt][1] = __builtin_amdgcn_mfma_f32_16x16x32_bf16(af, bf[1], acc[mt][1], 0, 0, 0);
        }
    }
    // epilogue: +contrib, *scale+shift, store
#pragma unroll
    for (int mt = 0; mt < 8; ++mt)
#pragma unroll
        for (int nt = 0; nt < 2; ++nt) {
            int p = pw + nt * 16 + (l & 15);
            int jj = ((p & 255) >> 5) & 3;
#pragma unroll
            for (int r = 0; r < 4; ++r) {
                int o = mt * 16 + (l >> 4) * 4 + r;
                float z = acc[mt][nt][r] + cvs[o * 4 + jj];
                out[(size_t)(b * 128 + o) * P_ + p] = fmaf(z, scl[o], shf[o]);
            }
        }
}

extern "C" void kernel_launch(void* const* d_in, const int* in_sizes, int n_in,
                              void* d_out, int out_size, void* d_ws, size_t ws_size,
                              hipStream_t stream) {
    const float* x = (const float*)d_in[0];
    const float* conv_w = (const float*)d_in[1];
    const float* conv_g = (const float*)d_in[2];
    const float* conv_b = (const float*)d_in[3];
    const float* final_w = (const float*)d_in[4];
    const float* final_g = (const float*)d_in[5];
    const float* final_b = (const float*)d_in[6];
    float* out = (float*)d_out;
    float* ws = (float*)d_ws;

    // exact fp32 pooled-path statistics (maxima feed tiny-n BNs -> must be exact)
    k_blockmax<<<512, 256, 0, stream>>>(x, ws);
    // Gram partials live in d_out scratch until k_reduceG; k_out overwrites d_out later
    k_gram<<<512, 256, 0, stream>>>(x, out);
    k_reduceG<<<256, 256, 0, stream>>>(out, ws);
    k_conv_pool<<<64, 256, 0, stream>>>(conv_w, ws);
    k_bnstats_d<<<2, 256, 0, stream>>>(conv_g, conv_b, ws);
    k_contrib<<<B_ * 64, 128, 0, stream>>>(final_w, ws);
    k_stats<<<128, 128, 0, stream>>>(final_w, final_g, final_b, ws);
    k_out<<<2048, 256, 0, stream>>>(x, final_w, ws, out);
}